// Round 1
// baseline (14576.341 us; speedup 1.0000x reference)
//
#include <hip/hip_runtime.h>

// ---------------------------------------------------------------------------
// multiStepModel: LSTM encoder (T=365) -> relu -> constant-input LSTM decoder
// (90 steps) -> relu -> FC.  Persistent cooperative kernel: the recurrence is
// 455 sequential steps, so we keep one workgroup per (batch-slice x hidden-
// slice) tile resident for the whole sequence with weights in LDS, and use a
// hand-rolled device-scope grid barrier between steps.  fp32 everywhere
// (bit-accurate vs reference within ~1e-5).
// ---------------------------------------------------------------------------

namespace {
constexpr int B = 128, T = 365, IN = 64, COV = 256, H = 512, OUTL = 90;
constexpr int GB = 4;            // batch groups
constexpr int GJ = 64;           // hidden groups
constexpr int NWG = GB * GJ;     // 256 workgroups (1 per CU, LDS ~154KB)
constexpr int NT = 256;          // threads per WG
constexpr int BS = B / GB;       // 32 batch rows per WG
constexpr int HU = H / GJ;       // 8 hidden units per WG
constexpr int NR = 4 * HU;       // 32 gate rows per WG (i,f,g,o x 8)
constexpr int KG = H / 4;        // 128 float4 granules of the hh K-dim
constexpr int KX = IN / 4;       // 16 granules of the x K-dim
}

__device__ float g_h[2][B][H];             // double-buffered hidden state
__device__ float g_part[OUTL][GJ][B];      // per-hidden-group FC partials
__device__ int   g_bar;                    // monotonic barrier counter

__device__ __forceinline__ float sigf(float x) { return 1.0f / (1.0f + expf(-x)); }

__device__ __forceinline__ float4 fma4(float4 a, float4 b, float4 c) {
  c.x = fmaf(a.x, b.x, c.x); c.y = fmaf(a.y, b.y, c.y);
  c.z = fmaf(a.z, b.z, c.z); c.w = fmaf(a.w, b.w, c.w);
  return c;
}
__device__ __forceinline__ float hsum4(float4 a) { return (a.x + a.y) + (a.z + a.w); }

// Device-scope grid barrier: monotonic counter, agent-scope fences handle
// cross-XCD L2 non-coherence (G16).  nb = 1,2,3,... uniform across all WGs.
__device__ __forceinline__ void grid_barrier(int nb) {
  __syncthreads();                       // drains vmcnt: all WG stores done
  if (threadIdx.x == 0) {
    __threadfence();                     // release: wb L2 so h' is visible
    atomicAdd(&g_bar, 1);                // device-scope
    const int target = nb * NWG;
    while (__hip_atomic_load(&g_bar, __ATOMIC_RELAXED, __HIP_MEMORY_SCOPE_AGENT) < target)
      __builtin_amdgcn_s_sleep(4);
    __threadfence();                     // acquire: inv L1/L2 before h reads
  }
  __syncthreads();
}

__global__ void __launch_bounds__(64) k_init() {
  if (threadIdx.x == 0) g_bar = 0;
}

__global__ void __launch_bounds__(NT, 1) k_lstm(
    const float* __restrict__ input, const float* __restrict__ covar,
    const float* __restrict__ W_ih1, const float* __restrict__ W_hh1,
    const float* __restrict__ b1,    const float* __restrict__ W_ih2,
    const float* __restrict__ W_hh2, const float* __restrict__ b2,
    const float* __restrict__ W_fc) {
  // LDS. Rows padded so row-stride % 32 banks == 4 floats -> <=2-way conflicts.
  __shared__ __align__(256) float4 w4[NR][KG + KX + 1];  // weights 32x(576+pad)
  __shared__ __align__(256) float4 h4[BS][KG + 1];       // staged h  32x(512+pad)
  __shared__ __align__(256) float4 x4[BS][KX + 1];       // staged x_t 32x(64+pad)
  __shared__ float g_lds[NR][33];                        // gate preacts (padded)
  __shared__ float pb_lds[NR][33];                       // covproj+b1 / proj2

  const int tid = threadIdx.x;
  const int gb  = blockIdx.x & (GB - 1);
  const int gj  = blockIdx.x >> 2;
  const int bg0 = gb * BS;       // first batch row of this WG
  const int j0  = gj * HU;       // first hidden unit of this WG

  // GEMM mapping: 2x2 outputs per thread, b in {bt,bt+16}, r in {rt,rt+16}
  const int bt = tid & 15;
  const int rt = tid >> 4;
  // cell-update mapping: one (batch,unit) pair per thread
  const int ub = tid & 31;
  const int uu = tid >> 5;

  int nbar = 0;

  // ---- stage encoder weights into LDS (resident for all 365 steps) ----
  for (int r = 0; r < NR; ++r) {
    const int row = (r >> 3) * H + j0 + (r & 7);  // gate q=r>>3, unit u=r&7
    const float4* src_hh = (const float4*)(W_hh1 + (size_t)row * H);
    for (int g = tid; g < KG; g += NT) w4[r][g] = src_hh[g];
    const float4* src_ih = (const float4*)(W_ih1 + (size_t)row * (IN + COV));
    if (tid < KX) w4[r][KG + tid] = src_ih[tid];
  }

  // ---- covariate projection + b1 (constant over t) -> pb_lds ----
  {
    const int r0 = rt, r1 = rt + 16;
    const int row0 = (r0 >> 3) * H + j0 + (r0 & 7);
    const int row1 = (r1 >> 3) * H + j0 + (r1 & 7);
    const float4* c0 = (const float4*)(covar + (size_t)(bg0 + bt) * COV);
    const float4* c1 = (const float4*)(covar + (size_t)(bg0 + bt + 16) * COV);
    const float4* w0 = (const float4*)(W_ih1 + (size_t)row0 * (IN + COV) + IN);
    const float4* w1 = (const float4*)(W_ih1 + (size_t)row1 * (IN + COV) + IN);
    float4 a00 = {0, 0, 0, 0}, a01 = a00, a10 = a00, a11 = a00;
    for (int k = 0; k < COV / 4; ++k) {
      float4 va = c0[k], vb = c1[k], wa = w0[k], wb = w1[k];
      a00 = fma4(va, wa, a00); a01 = fma4(va, wb, a01);
      a10 = fma4(vb, wa, a10); a11 = fma4(vb, wb, a11);
    }
    pb_lds[r0][bt]      = hsum4(a00) + b1[row0];
    pb_lds[r1][bt]      = hsum4(a01) + b1[row1];
    pb_lds[r0][bt + 16] = hsum4(a10) + b1[row0];
    pb_lds[r1][bt + 16] = hsum4(a11) + b1[row1];
  }

  float c_state = 0.0f;                  // LSTM cell state, register-resident
  float wfc = W_fc[j0 + uu];             // FC weight for this thread's unit

  // Stage h[b-slice] (full K) from global double buffer into LDS.
  auto stage_h = [&](int par) {
    const int bl = tid >> 3;
    const int g0 = tid & 7;
    const float4* hr = (const float4*)&g_h[par][bg0 + bl][0];
#pragma unroll
    for (int gi = 0; gi < 16; ++gi) h4[bl][g0 + gi * 8] = hr[g0 + gi * 8];
  };

  // Gate GEMM: g_lds[r][b] = sum_k h[b][k] Whh[r][k] (+ sum_i x[b][i] Wih[r][i])
  auto step_gemm = [&](bool with_h, bool with_x) {
    float4 a00 = {0, 0, 0, 0}, a01 = a00, a10 = a00, a11 = a00;
    const int b0 = bt, b1v = bt + 16;
    const int r0 = rt, r1 = rt + 16;
    if (with_h) {
      const float4* hp0 = &h4[b0][0];
      const float4* hp1 = &h4[b1v][0];
      const float4* wp0 = &w4[r0][0];
      const float4* wp1 = &w4[r1][0];
#pragma unroll 4
      for (int k = 0; k < KG; ++k) {
        float4 ha = hp0[k], hb = hp1[k], wa = wp0[k], wb = wp1[k];
        a00 = fma4(ha, wa, a00); a01 = fma4(ha, wb, a01);
        a10 = fma4(hb, wa, a10); a11 = fma4(hb, wb, a11);
      }
    }
    if (with_x) {
#pragma unroll
      for (int k = 0; k < KX; ++k) {
        float4 ha = x4[b0][k], hb = x4[b1v][k];
        float4 wa = w4[r0][KG + k], wb = w4[r1][KG + k];
        a00 = fma4(ha, wa, a00); a01 = fma4(ha, wb, a01);
        a10 = fma4(hb, wa, a10); a11 = fma4(hb, wb, a11);
      }
    }
    g_lds[r0][b0]  = hsum4(a00); g_lds[r1][b0]  = hsum4(a01);
    g_lds[r0][b1v] = hsum4(a10); g_lds[r1][b1v] = hsum4(a11);
  };

  // Pointwise LSTM cell; writes h' to global buffer. Returns raw h'.
  auto cell_update = [&](int wbuf, bool relu_store) -> float {
    float ip = g_lds[uu][ub]      + pb_lds[uu][ub];
    float fp = g_lds[8 + uu][ub]  + pb_lds[8 + uu][ub];
    float gp = g_lds[16 + uu][ub] + pb_lds[16 + uu][ub];
    float op = g_lds[24 + uu][ub] + pb_lds[24 + uu][ub];
    c_state = sigf(fp) * c_state + sigf(ip) * tanhf(gp);
    float hv = sigf(op) * tanhf(c_state);
    g_h[wbuf][bg0 + ub][j0 + uu] = relu_store ? fmaxf(hv, 0.0f) : hv;
    return hv;
  };

  // =================== encoder: 365 steps ===================
  for (int t = 0; t < T; ++t) {
    if (t > 0) stage_h(t & 1);
    {  // stage x_t
      const int bl = tid >> 3;
      const int g0 = tid & 7;
      const float4* xr = (const float4*)(input + ((size_t)(bg0 + bl) * T + t) * IN);
      x4[bl][g0] = xr[g0];
      x4[bl][g0 + 8] = xr[g0 + 8];
    }
    __syncthreads();
    step_gemm(t > 0, true);     // t==0: h=0, skip hh part
    __syncthreads();
    cell_update((t + 1) & 1, t == T - 1);  // last step stores relu(h_enc)
    grid_barrier(++nbar);
  }

  // =================== transition: proj2 = [relu(h_enc),covar] @ W_ih2^T + b2
  stage_h(1);                   // relu(h_enc) is in buffer 1
  __syncthreads();
  {
    const int b0 = bt, b1v = bt + 16;
    const int r0 = rt, r1 = rt + 16;
    const int row0 = (r0 >> 3) * H + j0 + (r0 & 7);
    const int row1 = (r1 >> 3) * H + j0 + (r1 & 7);
    const float4* w0 = (const float4*)(W_ih2 + (size_t)row0 * (H + COV));
    const float4* w1 = (const float4*)(W_ih2 + (size_t)row1 * (H + COV));
    float4 a00 = {0, 0, 0, 0}, a01 = a00, a10 = a00, a11 = a00;
    for (int k = 0; k < KG; ++k) {          // h part (from LDS)
      float4 ha = h4[b0][k], hb = h4[b1v][k], wa = w0[k], wb = w1[k];
      a00 = fma4(ha, wa, a00); a01 = fma4(ha, wb, a01);
      a10 = fma4(hb, wa, a10); a11 = fma4(hb, wb, a11);
    }
    const float4* c0 = (const float4*)(covar + (size_t)(bg0 + b0) * COV);
    const float4* c1 = (const float4*)(covar + (size_t)(bg0 + b1v) * COV);
    for (int k = 0; k < COV / 4; ++k) {     // covar part (global, L1/L2-hot)
      float4 ha = c0[k], hb = c1[k], wa = w0[KG + k], wb = w1[KG + k];
      a00 = fma4(ha, wa, a00); a01 = fma4(ha, wb, a01);
      a10 = fma4(hb, wa, a10); a11 = fma4(hb, wb, a11);
    }
    pb_lds[r0][b0]  = hsum4(a00) + b2[row0];
    pb_lds[r1][b0]  = hsum4(a01) + b2[row1];
    pb_lds[r0][b1v] = hsum4(a10) + b2[row0];
    pb_lds[r1][b1v] = hsum4(a11) + b2[row1];
  }
  // stage decoder recurrent weights over the encoder ones (WG-private LDS)
  for (int r = 0; r < NR; ++r) {
    const int row = (r >> 3) * H + j0 + (r & 7);
    const float4* src = (const float4*)(W_hh2 + (size_t)row * H);
    for (int g = tid; g < KG; g += NT) w4[r][g] = src[g];
  }
  c_state = 0.0f;
  grid_barrier(++nbar);   // protects g_h[1] (read above) from decoder ot=0 write

  // =================== decoder: 90 steps ===================
  for (int ot = 0; ot < OUTL; ++ot) {
    if (ot > 0) stage_h(ot & 1);
    __syncthreads();
    step_gemm(ot > 0, false);   // ot==0: h=0 -> gates = proj2 only
    __syncthreads();
    float hv = cell_update((ot + 1) & 1, false);
    float fcv = fmaxf(hv, 0.0f) * wfc;   // relu(h) * W_fc[j]
    __syncthreads();                     // g_lds reuse guard
    g_lds[uu][ub] = fcv;                 // rows 0..7 hold FC partials
    __syncthreads();
    if (tid < BS) {
      float s = 0.0f;
#pragma unroll
      for (int u = 0; u < HU; ++u) s += g_lds[u][tid];
      g_part[ot][gj][bg0 + tid] = s;
    }
    grid_barrier(++nbar);
  }
}

__global__ void __launch_bounds__(256) k_reduce(const float* __restrict__ b_fc,
                                                float* __restrict__ out) {
  int id = blockIdx.x * 256 + threadIdx.x;
  if (id >= B * OUTL) return;
  int b = id / OUTL, ot = id - b * OUTL;
  float s = b_fc[0];
#pragma unroll 8
  for (int g = 0; g < GJ; ++g) s += g_part[ot][g][b];
  out[id] = s;   // out[b][ot], row-major == id
}

extern "C" void kernel_launch(void* const* d_in, const int* in_sizes, int n_in,
                              void* d_out, int out_size, void* d_ws, size_t ws_size,
                              hipStream_t stream) {
  (void)in_sizes; (void)n_in; (void)d_ws; (void)ws_size; (void)out_size;
  const float* input = (const float*)d_in[0];
  const float* covar = (const float*)d_in[1];
  const float* W_ih1 = (const float*)d_in[2];
  const float* W_hh1 = (const float*)d_in[3];
  const float* b1    = (const float*)d_in[4];
  const float* W_ih2 = (const float*)d_in[5];
  const float* W_hh2 = (const float*)d_in[6];
  const float* b2    = (const float*)d_in[7];
  const float* W_fc  = (const float*)d_in[8];
  const float* b_fc  = (const float*)d_in[9];

  k_init<<<dim3(1), dim3(64), 0, stream>>>();
  k_lstm<<<dim3(NWG), dim3(NT), 0, stream>>>(input, covar, W_ih1, W_hh1, b1,
                                             W_ih2, W_hh2, b2, W_fc);
  k_reduce<<<dim3((B * OUTL + 255) / 256), dim3(256), 0, stream>>>(
      b_fc, (float*)d_out);
}

// Round 2
// 10335.197 us; speedup vs baseline: 1.4104x; 1.4104x over previous
//
#include <hip/hip_runtime.h>

// ---------------------------------------------------------------------------
// multiStepModel: LSTM encoder (T=365) -> relu -> constant-input LSTM decoder
// (90 steps) -> relu -> FC.  Persistent cooperative kernel: 455 sequential
// steps; one WG per (batch-slice x hidden-slice) tile, weights LDS-resident.
// R2: per-batch-group (64-WG) flag barriers, one flag word per WG
// (contention-free), wave-wide poll, split-phase x staging inside the wait.
// ---------------------------------------------------------------------------

namespace {
constexpr int B = 128, T = 365, IN = 64, COV = 256, H = 512, OUTL = 90;
constexpr int GB = 4;            // batch groups (independent barrier quorums)
constexpr int GJ = 64;           // hidden groups
constexpr int NWG = GB * GJ;     // 256 workgroups, 1/CU (LDS ~154KB)
constexpr int NT = 256;          // threads per WG
constexpr int BS = B / GB;       // 32 batch rows per WG
constexpr int HU = H / GJ;       // 8 hidden units per WG
constexpr int NR = 4 * HU;       // 32 gate rows per WG
constexpr int KG = H / 4;        // 128 float4 granules of hh K-dim
constexpr int KX = IN / 4;       // 16 granules of x K-dim
}

__device__ float g_h[2][B][H];             // double-buffered hidden state
__device__ float g_part[OUTL][GJ][B];      // per-hidden-group FC partials
__device__ int   g_flag[GB][64];           // per-WG monotonic barrier flags

__device__ __forceinline__ float sigf(float x) { return 1.0f / (1.0f + expf(-x)); }

__device__ __forceinline__ float4 fma4(float4 a, float4 b, float4 c) {
  c.x = fmaf(a.x, b.x, c.x); c.y = fmaf(a.y, b.y, c.y);
  c.z = fmaf(a.z, b.z, c.z); c.w = fmaf(a.w, b.w, c.w);
  return c;
}
__device__ __forceinline__ float hsum4(float4 a) { return (a.x + a.y) + (a.z + a.w); }

__global__ void __launch_bounds__(256) k_init() {
  int t = threadIdx.x;
  if (t < GB * 64) g_flag[t >> 6][t & 63] = 0;
}

__global__ void __launch_bounds__(NT, 1) k_lstm(
    const float* __restrict__ input, const float* __restrict__ covar,
    const float* __restrict__ W_ih1, const float* __restrict__ W_hh1,
    const float* __restrict__ b1,    const float* __restrict__ W_ih2,
    const float* __restrict__ W_hh2, const float* __restrict__ b2,
    const float* __restrict__ W_fc) {
  // LDS. Rows padded so row-stride % 32 banks == 4 floats -> <=2-way conflicts.
  __shared__ __align__(256) float4 w4[NR][KG + KX + 1];  // weights 32x(576+pad)
  __shared__ __align__(256) float4 h4[BS][KG + 1];       // staged h  32x(512+pad)
  __shared__ __align__(256) float4 x4[BS][KX + 1];       // staged x_t
  __shared__ float g_lds[NR][33];                        // gate preacts
  __shared__ float pb_lds[NR][33];                       // covproj+b1 / proj2

  const int tid = threadIdx.x;
  const int gb  = blockIdx.x & (GB - 1);
  const int gj  = blockIdx.x >> 2;
  const int bg0 = gb * BS;
  const int j0  = gj * HU;

  const int bt = tid & 15;       // GEMM mapping: 2x2 outputs per thread
  const int rt = tid >> 4;
  const int ub = tid & 31;       // cell mapping: one (batch,unit) per thread
  const int uu = tid >> 5;

  int nbar = 0;

  // ---- per-gb-group barrier: contention-free flag publish + wave-wide poll.
  // Optional split-phase x_{tn} staging hidden inside the wait.
  auto gbar = [&](int nb, bool with_x, int tn) {
    __syncthreads();                     // all h'/partial stores complete (L2)
    if (tid == 0) {
      __threadfence();                   // release: wb XCD L2 (cross-XCD vis)
      atomicExch(&g_flag[gb][gj], nb);   // device-scope RMW, distinct addr
    }
    if (with_x) {                        // stage x_{tn} while waiting
      const int bl = tid >> 3, g0 = tid & 7;
      const float4* xr = (const float4*)(input + ((size_t)(bg0 + bl) * T + tn) * IN);
      x4[bl][g0] = xr[g0];
      x4[bl][g0 + 8] = xr[g0 + 8];
    }
    if (tid < 64) {                      // lane i watches group-member i
      while (__hip_atomic_load(&g_flag[gb][tid], __ATOMIC_RELAXED,
                               __HIP_MEMORY_SCOPE_AGENT) < nb)
        __builtin_amdgcn_s_sleep(1);
    }
    if (tid == 0) __threadfence();       // acquire: inv L1/L2 before h reads
    __syncthreads();
  };

  // ---- stage encoder weights into LDS (resident for all 365 steps) ----
  for (int r = 0; r < NR; ++r) {
    const int row = (r >> 3) * H + j0 + (r & 7);  // gate q=r>>3, unit u=r&7
    const float4* src_hh = (const float4*)(W_hh1 + (size_t)row * H);
    for (int g = tid; g < KG; g += NT) w4[r][g] = src_hh[g];
    const float4* src_ih = (const float4*)(W_ih1 + (size_t)row * (IN + COV));
    if (tid < KX) w4[r][KG + tid] = src_ih[tid];
  }

  // ---- covariate projection + b1 (constant over t) -> pb_lds ----
  {
    const int r0 = rt, r1 = rt + 16;
    const int row0 = (r0 >> 3) * H + j0 + (r0 & 7);
    const int row1 = (r1 >> 3) * H + j0 + (r1 & 7);
    const float4* c0 = (const float4*)(covar + (size_t)(bg0 + bt) * COV);
    const float4* c1 = (const float4*)(covar + (size_t)(bg0 + bt + 16) * COV);
    const float4* w0 = (const float4*)(W_ih1 + (size_t)row0 * (IN + COV) + IN);
    const float4* w1 = (const float4*)(W_ih1 + (size_t)row1 * (IN + COV) + IN);
    float4 a00 = {0, 0, 0, 0}, a01 = a00, a10 = a00, a11 = a00;
    for (int k = 0; k < COV / 4; ++k) {
      float4 va = c0[k], vb = c1[k], wa = w0[k], wb = w1[k];
      a00 = fma4(va, wa, a00); a01 = fma4(va, wb, a01);
      a10 = fma4(vb, wa, a10); a11 = fma4(vb, wb, a11);
    }
    pb_lds[r0][bt]      = hsum4(a00) + b1[row0];
    pb_lds[r1][bt]      = hsum4(a01) + b1[row1];
    pb_lds[r0][bt + 16] = hsum4(a10) + b1[row0];
    pb_lds[r1][bt + 16] = hsum4(a11) + b1[row1];
  }

  float c_state = 0.0f;
  float wfc = W_fc[j0 + uu];

  auto stage_h = [&](int par) {
    const int bl = tid >> 3;
    const int g0 = tid & 7;
    const float4* hr = (const float4*)&g_h[par][bg0 + bl][0];
#pragma unroll
    for (int gi = 0; gi < 16; ++gi) h4[bl][g0 + gi * 8] = hr[g0 + gi * 8];
  };

  auto step_gemm = [&](bool with_h, bool with_x) {
    float4 a00 = {0, 0, 0, 0}, a01 = a00, a10 = a00, a11 = a00;
    const int b0 = bt, b1v = bt + 16;
    const int r0 = rt, r1 = rt + 16;
    if (with_h) {
      const float4* hp0 = &h4[b0][0];
      const float4* hp1 = &h4[b1v][0];
      const float4* wp0 = &w4[r0][0];
      const float4* wp1 = &w4[r1][0];
#pragma unroll 4
      for (int k = 0; k < KG; ++k) {
        float4 ha = hp0[k], hb = hp1[k], wa = wp0[k], wb = wp1[k];
        a00 = fma4(ha, wa, a00); a01 = fma4(ha, wb, a01);
        a10 = fma4(hb, wa, a10); a11 = fma4(hb, wb, a11);
      }
    }
    if (with_x) {
#pragma unroll
      for (int k = 0; k < KX; ++k) {
        float4 ha = x4[b0][k], hb = x4[b1v][k];
        float4 wa = w4[r0][KG + k], wb = w4[r1][KG + k];
        a00 = fma4(ha, wa, a00); a01 = fma4(ha, wb, a01);
        a10 = fma4(hb, wa, a10); a11 = fma4(hb, wb, a11);
      }
    }
    g_lds[r0][b0]  = hsum4(a00); g_lds[r1][b0]  = hsum4(a01);
    g_lds[r0][b1v] = hsum4(a10); g_lds[r1][b1v] = hsum4(a11);
  };

  auto cell_update = [&](int wbuf, bool relu_store) -> float {
    float ip = g_lds[uu][ub]      + pb_lds[uu][ub];
    float fp = g_lds[8 + uu][ub]  + pb_lds[8 + uu][ub];
    float gp = g_lds[16 + uu][ub] + pb_lds[16 + uu][ub];
    float op = g_lds[24 + uu][ub] + pb_lds[24 + uu][ub];
    c_state = sigf(fp) * c_state + sigf(ip) * tanhf(gp);
    float hv = sigf(op) * tanhf(c_state);
    g_h[wbuf][bg0 + ub][j0 + uu] = relu_store ? fmaxf(hv, 0.0f) : hv;
    return hv;
  };

  // =================== encoder: 365 steps ===================
  {  // stage x_0
    const int bl = tid >> 3, g0 = tid & 7;
    const float4* xr = (const float4*)(input + (size_t)(bg0 + bl) * T * IN);
    x4[bl][g0] = xr[g0];
    x4[bl][g0 + 8] = xr[g0 + 8];
  }
  for (int t = 0; t < T; ++t) {
    if (t > 0) stage_h(t & 1);
    __syncthreads();
    step_gemm(t > 0, true);     // t==0: h=0, skip hh part
    __syncthreads();
    cell_update((t + 1) & 1, t == T - 1);  // last step stores relu(h_enc)
    gbar(++nbar, t + 1 < T, t + 1);        // stage x_{t+1} inside the wait
  }

  // ====== transition: proj2 = [relu(h_enc),covar] @ W_ih2^T + b2 ======
  stage_h(1);                   // relu(h_enc) is in buffer 1
  __syncthreads();
  {
    const int b0 = bt, b1v = bt + 16;
    const int r0 = rt, r1 = rt + 16;
    const int row0 = (r0 >> 3) * H + j0 + (r0 & 7);
    const int row1 = (r1 >> 3) * H + j0 + (r1 & 7);
    const float4* w0 = (const float4*)(W_ih2 + (size_t)row0 * (H + COV));
    const float4* w1 = (const float4*)(W_ih2 + (size_t)row1 * (H + COV));
    float4 a00 = {0, 0, 0, 0}, a01 = a00, a10 = a00, a11 = a00;
    for (int k = 0; k < KG; ++k) {          // h part (from LDS)
      float4 ha = h4[b0][k], hb = h4[b1v][k], wa = w0[k], wb = w1[k];
      a00 = fma4(ha, wa, a00); a01 = fma4(ha, wb, a01);
      a10 = fma4(hb, wa, a10); a11 = fma4(hb, wb, a11);
    }
    const float4* c0 = (const float4*)(covar + (size_t)(bg0 + b0) * COV);
    const float4* c1 = (const float4*)(covar + (size_t)(bg0 + b1v) * COV);
    for (int k = 0; k < COV / 4; ++k) {     // covar part (global, cache-hot)
      float4 ha = c0[k], hb = c1[k], wa = w0[KG + k], wb = w1[KG + k];
      a00 = fma4(ha, wa, a00); a01 = fma4(ha, wb, a01);
      a10 = fma4(hb, wa, a10); a11 = fma4(hb, wb, a11);
    }
    pb_lds[r0][b0]  = hsum4(a00) + b2[row0];
    pb_lds[r1][b0]  = hsum4(a01) + b2[row1];
    pb_lds[r0][b1v] = hsum4(a10) + b2[row0];
    pb_lds[r1][b1v] = hsum4(a11) + b2[row1];
  }
  // stage decoder recurrent weights over the encoder ones (WG-private LDS)
  for (int r = 0; r < NR; ++r) {
    const int row = (r >> 3) * H + j0 + (r & 7);
    const float4* src = (const float4*)(W_hh2 + (size_t)row * H);
    for (int g = tid; g < KG; g += NT) w4[r][g] = src[g];
  }
  c_state = 0.0f;
  gbar(++nbar, false, 0);   // protect g_h[1] (read above) from ot=0 write

  // =================== decoder: 90 steps ===================
  for (int ot = 0; ot < OUTL; ++ot) {
    if (ot > 0) stage_h(ot & 1);
    __syncthreads();
    step_gemm(ot > 0, false);   // ot==0: h=0 -> gates = proj2 only
    __syncthreads();
    float hv = cell_update((ot + 1) & 1, false);
    float fcv = fmaxf(hv, 0.0f) * wfc;   // relu(h) * W_fc[j]
    __syncthreads();                     // g_lds reuse guard
    g_lds[uu][ub] = fcv;                 // rows 0..7 hold FC partials
    __syncthreads();
    if (tid < BS) {
      float s = 0.0f;
#pragma unroll
      for (int u = 0; u < HU; ++u) s += g_lds[u][tid];
      g_part[ot][gj][bg0 + tid] = s;
    }
    gbar(++nbar, false, 0);
  }
}

__global__ void __launch_bounds__(256) k_reduce(const float* __restrict__ b_fc,
                                                float* __restrict__ out) {
  int id = blockIdx.x * 256 + threadIdx.x;
  if (id >= B * OUTL) return;
  int b = id / OUTL, ot = id - b * OUTL;
  float s = b_fc[0];
#pragma unroll 8
  for (int g = 0; g < GJ; ++g) s += g_part[ot][g][b];
  out[id] = s;   // out[b][ot], row-major == id
}

extern "C" void kernel_launch(void* const* d_in, const int* in_sizes, int n_in,
                              void* d_out, int out_size, void* d_ws, size_t ws_size,
                              hipStream_t stream) {
  (void)in_sizes; (void)n_in; (void)d_ws; (void)ws_size; (void)out_size;
  const float* input = (const float*)d_in[0];
  const float* covar = (const float*)d_in[1];
  const float* W_ih1 = (const float*)d_in[2];
  const float* W_hh1 = (const float*)d_in[3];
  const float* b1    = (const float*)d_in[4];
  const float* W_ih2 = (const float*)d_in[5];
  const float* W_hh2 = (const float*)d_in[6];
  const float* b2    = (const float*)d_in[7];
  const float* W_fc  = (const float*)d_in[8];
  const float* b_fc  = (const float*)d_in[9];

  k_init<<<dim3(1), dim3(256), 0, stream>>>();
  k_lstm<<<dim3(NWG), dim3(NT), 0, stream>>>(input, covar, W_ih1, W_hh1, b1,
                                             W_ih2, W_hh2, b2, W_fc);
  k_reduce<<<dim3((B * OUTL + 255) / 256), dim3(256), 0, stream>>>(
      b_fc, (float*)d_out);
}

// Round 4
// 4871.782 us; speedup vs baseline: 2.9920x; 2.1214x over previous
//
#include <hip/hip_runtime.h>

// ---------------------------------------------------------------------------
// multiStepModel: LSTM encoder (T=365) -> relu -> constant-input LSTM decoder
// (90 steps) -> relu -> FC.  Persistent cooperative kernel, 1 WG/CU, weights
// LDS-resident.  R4: cross-WG h exchange via __hip_atomic relaxed AGENT-scope
// loads/stores (compiler-emitted coherence bits: write-through stores,
// L2-bypassing loads) -> NO __threadfence, NO per-step L2 wbl2/inv storm,
// and no hand-rolled asm (R3's crash).  h-load latency hidden under x-GEMM.
// ---------------------------------------------------------------------------

namespace {
constexpr int B = 128, T = 365, IN = 64, COV = 256, H = 512, OUTL = 90;
constexpr int GB = 4;            // batch groups (independent barrier quorums)
constexpr int GJ = 64;           // hidden groups
constexpr int NWG = GB * GJ;     // 256 workgroups, 1/CU (LDS ~154KB)
constexpr int NT = 256;          // threads per WG
constexpr int BS = B / GB;       // 32 batch rows per WG
constexpr int HU = H / GJ;       // 8 hidden units per WG
constexpr int NR = 4 * HU;       // 32 gate rows per WG
constexpr int KG = H / 4;        // 128 float4 granules of hh K-dim
constexpr int KX = IN / 4;       // 16 granules of x K-dim
}

using ull = unsigned long long;

__device__ float g_h[2][B][H];             // double-buffered hidden state
__device__ float g_part[OUTL][GJ][B];      // per-hidden-group FC partials
__device__ int   g_flag[GB][64];           // per-WG monotonic barrier flags

__device__ __forceinline__ float sigf(float x) { return 1.0f / (1.0f + expf(-x)); }

__device__ __forceinline__ float4 fma4(float4 a, float4 b, float4 c) {
  c.x = fmaf(a.x, b.x, c.x); c.y = fmaf(a.y, b.y, c.y);
  c.z = fmaf(a.z, b.z, c.z); c.w = fmaf(a.w, b.w, c.w);
  return c;
}
__device__ __forceinline__ float hsum4(float4 a) { return (a.x + a.y) + (a.z + a.w); }

__global__ void __launch_bounds__(256) k_init() {
  int t = threadIdx.x;
  if (t < GB * 64) g_flag[t >> 6][t & 63] = 0;
}

__global__ void __launch_bounds__(NT, 1) k_lstm(
    const float* __restrict__ input, const float* __restrict__ covar,
    const float* __restrict__ W_ih1, const float* __restrict__ W_hh1,
    const float* __restrict__ b1,    const float* __restrict__ W_ih2,
    const float* __restrict__ W_hh2, const float* __restrict__ b2,
    const float* __restrict__ W_fc) {
  // LDS. Rows padded so row-stride % 32 banks == 4 floats -> <=2-way conflicts.
  __shared__ __align__(256) float4 w4[NR][KG + KX + 1];  // weights 32x(576+pad)
  __shared__ __align__(256) float4 h4[BS][KG + 1];       // staged h  32x(512+pad)
  __shared__ __align__(256) float4 x4[BS][KX + 1];       // staged x_t
  __shared__ float g_lds[NR][33];                        // gate preacts
  __shared__ float pb_lds[NR][33];                       // covproj+b1 / proj2

  const int tid = threadIdx.x;
  const int gb  = blockIdx.x & (GB - 1);
  const int gj  = blockIdx.x >> 2;
  const int bg0 = gb * BS;
  const int j0  = gj * HU;

  const int bt = tid & 15;       // GEMM mapping: 2x2 outputs per thread
  const int rt = tid >> 4;
  const int ub = tid & 31;       // cell mapping: one (batch,unit) per thread
  const int uu = tid >> 5;
  const int bl = tid >> 3;       // staging mapping: row 0..31
  const int sg = tid & 7;        // staging mapping: column group 0..7

  int nbar = 0;

  // Per-gb-group barrier.  Release = __syncthreads (compiler drains vmcnt(0)
  // before s_barrier) + one flag atomicExch per WG (distinct addresses).
  // No acquire fence needed: h reads are AGENT-scope (L2-bypassing).
  auto gbar = [&](int nb, bool with_x, int tn) {
    __syncthreads();
    if (tid == 0) atomicExch(&g_flag[gb][gj], nb);   // device-scope, at LLC
    if (with_x) {                                    // stage x_{tn} in the wait
      const float4* xr = (const float4*)(input + ((size_t)(bg0 + bl) * T + tn) * IN);
      x4[bl][sg] = xr[sg];
      x4[bl][sg + 8] = xr[sg + 8];
    }
    if (tid < 64) {                                  // lane i watches member i
      while (__hip_atomic_load(&g_flag[gb][tid], __ATOMIC_RELAXED,
                               __HIP_MEMORY_SCOPE_AGENT) < nb)
        __builtin_amdgcn_s_sleep(1);
    }
    __syncthreads();
  };

  // Coherent h staging, split into issue (loads -> regs) and commit (-> LDS).
  auto load_h = [&](int par, ull (&tmp)[32]) {
    const ull* hr = (const ull*)&g_h[par][bg0 + bl][0];   // 256 ull per row
#pragma unroll
    for (int i = 0; i < 32; ++i)
      tmp[i] = __hip_atomic_load(hr + sg + i * 8, __ATOMIC_RELAXED,
                                 __HIP_MEMORY_SCOPE_AGENT);
  };
  auto commit_h = [&](ull (&tmp)[32]) {
    ull* hl = (ull*)&h4[bl][0];
#pragma unroll
    for (int i = 0; i < 32; ++i) hl[sg + i * 8] = tmp[i];
  };

  // ---- stage encoder weights into LDS (resident for all 365 steps) ----
  for (int r = 0; r < NR; ++r) {
    const int row = (r >> 3) * H + j0 + (r & 7);  // gate q=r>>3, unit u=r&7
    const float4* src_hh = (const float4*)(W_hh1 + (size_t)row * H);
    for (int g = tid; g < KG; g += NT) w4[r][g] = src_hh[g];
    const float4* src_ih = (const float4*)(W_ih1 + (size_t)row * (IN + COV));
    if (tid < KX) w4[r][KG + tid] = src_ih[tid];
  }

  // ---- covariate projection + b1 (constant over t) -> pb_lds ----
  {
    const int r0 = rt, r1 = rt + 16;
    const int row0 = (r0 >> 3) * H + j0 + (r0 & 7);
    const int row1 = (r1 >> 3) * H + j0 + (r1 & 7);
    const float4* c0 = (const float4*)(covar + (size_t)(bg0 + bt) * COV);
    const float4* c1 = (const float4*)(covar + (size_t)(bg0 + bt + 16) * COV);
    const float4* w0 = (const float4*)(W_ih1 + (size_t)row0 * (IN + COV) + IN);
    const float4* w1 = (const float4*)(W_ih1 + (size_t)row1 * (IN + COV) + IN);
    float4 a00 = {0, 0, 0, 0}, a01 = a00, a10 = a00, a11 = a00;
    for (int k = 0; k < COV / 4; ++k) {
      float4 va = c0[k], vb = c1[k], wa = w0[k], wb = w1[k];
      a00 = fma4(va, wa, a00); a01 = fma4(va, wb, a01);
      a10 = fma4(vb, wa, a10); a11 = fma4(vb, wb, a11);
    }
    pb_lds[r0][bt]      = hsum4(a00) + b1[row0];
    pb_lds[r1][bt]      = hsum4(a01) + b1[row1];
    pb_lds[r0][bt + 16] = hsum4(a10) + b1[row0];
    pb_lds[r1][bt + 16] = hsum4(a11) + b1[row1];
  }

  float c_state = 0.0f;
  float wfc = W_fc[j0 + uu];

  // x-part of the gate GEMM (LDS-only; overlaps in-flight h loads)
  auto x_gemm = [&](float4& a00, float4& a01, float4& a10, float4& a11) {
#pragma unroll
    for (int k = 0; k < KX; ++k) {
      float4 ha = x4[bt][k], hb = x4[bt + 16][k];
      float4 wa = w4[rt][KG + k], wb = w4[rt + 16][KG + k];
      a00 = fma4(ha, wa, a00); a01 = fma4(ha, wb, a01);
      a10 = fma4(hb, wa, a10); a11 = fma4(hb, wb, a11);
    }
  };

  // h-part of the gate GEMM (reads h4 staged in LDS)
  auto h_gemm = [&](float4& a00, float4& a01, float4& a10, float4& a11) {
    const float4* hp0 = &h4[bt][0];
    const float4* hp1 = &h4[bt + 16][0];
    const float4* wp0 = &w4[rt][0];
    const float4* wp1 = &w4[rt + 16][0];
#pragma unroll 4
    for (int k = 0; k < KG; ++k) {
      float4 ha = hp0[k], hb = hp1[k], wa = wp0[k], wb = wp1[k];
      a00 = fma4(ha, wa, a00); a01 = fma4(ha, wb, a01);
      a10 = fma4(hb, wa, a10); a11 = fma4(hb, wb, a11);
    }
  };

  auto put_gates = [&](float4 a00, float4 a01, float4 a10, float4 a11) {
    g_lds[rt][bt]           = hsum4(a00); g_lds[rt + 16][bt]      = hsum4(a01);
    g_lds[rt][bt + 16]      = hsum4(a10); g_lds[rt + 16][bt + 16] = hsum4(a11);
  };

  // Pointwise LSTM cell; h' published write-through via AGENT-scope store.
  auto cell_update = [&](int wbuf, bool relu_store) -> float {
    float ip = g_lds[uu][ub]      + pb_lds[uu][ub];
    float fp = g_lds[8 + uu][ub]  + pb_lds[8 + uu][ub];
    float gp = g_lds[16 + uu][ub] + pb_lds[16 + uu][ub];
    float op = g_lds[24 + uu][ub] + pb_lds[24 + uu][ub];
    c_state = sigf(fp) * c_state + sigf(ip) * tanhf(gp);
    float hv = sigf(op) * tanhf(c_state);
    __hip_atomic_store(&g_h[wbuf][bg0 + ub][j0 + uu],
                       relu_store ? fmaxf(hv, 0.0f) : hv,
                       __ATOMIC_RELAXED, __HIP_MEMORY_SCOPE_AGENT);
    return hv;
  };

  // =================== encoder: 365 steps ===================
  {  // stage x_0
    const float4* xr = (const float4*)(input + (size_t)(bg0 + bl) * T * IN);
    x4[bl][sg] = xr[sg];
    x4[bl][sg + 8] = xr[sg + 8];
  }
  __syncthreads();   // w4/pb_lds/x4 ready for t=0

  for (int t = 0; t < T; ++t) {
    ull tmp[32];
    if (t > 0) load_h(t & 1, tmp);         // issue LLC loads (latency hidden)
    float4 a00 = {0, 0, 0, 0}, a01 = a00, a10 = a00, a11 = a00;
    x_gemm(a00, a01, a10, a11);            // overlaps the loads
    if (t > 0) commit_h(tmp);              // waitcnt + ds_write
    __syncthreads();                       // h4 ready; g_lds free to overwrite
    if (t > 0) h_gemm(a00, a01, a10, a11);
    put_gates(a00, a01, a10, a11);
    __syncthreads();
    cell_update((t + 1) & 1, t == T - 1);  // last step stores relu(h_enc)
    gbar(++nbar, t + 1 < T, t + 1);        // stage x_{t+1} inside the wait
  }

  // ====== transition: proj2 = [relu(h_enc),covar] @ W_ih2^T + b2 ======
  {
    ull tmp[32];
    load_h(1, tmp);              // relu(h_enc) is in buffer 1
    commit_h(tmp);
  }
  __syncthreads();
  {
    const int b0 = bt, b1v = bt + 16;
    const int r0 = rt, r1 = rt + 16;
    const int row0 = (r0 >> 3) * H + j0 + (r0 & 7);
    const int row1 = (r1 >> 3) * H + j0 + (r1 & 7);
    const float4* w0 = (const float4*)(W_ih2 + (size_t)row0 * (H + COV));
    const float4* w1 = (const float4*)(W_ih2 + (size_t)row1 * (H + COV));
    float4 a00 = {0, 0, 0, 0}, a01 = a00, a10 = a00, a11 = a00;
    for (int k = 0; k < KG; ++k) {          // h part (from LDS)
      float4 ha = h4[b0][k], hb = h4[b1v][k], wa = w0[k], wb = w1[k];
      a00 = fma4(ha, wa, a00); a01 = fma4(ha, wb, a01);
      a10 = fma4(hb, wa, a10); a11 = fma4(hb, wb, a11);
    }
    const float4* c0 = (const float4*)(covar + (size_t)(bg0 + b0) * COV);
    const float4* c1 = (const float4*)(covar + (size_t)(bg0 + b1v) * COV);
    for (int k = 0; k < COV / 4; ++k) {     // covar part (global, cache-hot)
      float4 ha = c0[k], hb = c1[k], wa = w0[KG + k], wb = w1[KG + k];
      a00 = fma4(ha, wa, a00); a01 = fma4(ha, wb, a01);
      a10 = fma4(hb, wa, a10); a11 = fma4(hb, wb, a11);
    }
    pb_lds[r0][b0]  = hsum4(a00) + b2[row0];
    pb_lds[r1][b0]  = hsum4(a01) + b2[row1];
    pb_lds[r0][b1v] = hsum4(a10) + b2[row0];
    pb_lds[r1][b1v] = hsum4(a11) + b2[row1];
  }
  // stage decoder recurrent weights over the encoder ones (WG-private LDS)
  for (int r = 0; r < NR; ++r) {
    const int row = (r >> 3) * H + j0 + (r & 7);
    const float4* src = (const float4*)(W_hh2 + (size_t)row * H);
    for (int g = tid; g < KG; g += NT) w4[r][g] = src[g];
  }
  c_state = 0.0f;
  gbar(++nbar, false, 0);   // protect g_h[1] (read above) from ot=0 write

  // =================== decoder: 90 steps ===================
  for (int ot = 0; ot < OUTL; ++ot) {
    if (ot > 0) {
      ull tmp[32];
      load_h(ot & 1, tmp);
      commit_h(tmp);
    }
    __syncthreads();                       // h4 ready; g_lds free
    float4 a00 = {0, 0, 0, 0}, a01 = a00, a10 = a00, a11 = a00;
    if (ot > 0) h_gemm(a00, a01, a10, a11);
    put_gates(a00, a01, a10, a11);         // ot==0: gates = proj2 only
    __syncthreads();
    float hv = cell_update((ot + 1) & 1, false);
    float fcv = fmaxf(hv, 0.0f) * wfc;     // relu(h) * W_fc[j]
    __syncthreads();                       // g_lds reuse guard
    g_lds[uu][ub] = fcv;                   // rows 0..7 hold FC partials
    __syncthreads();
    if (tid < BS) {
      float s = 0.0f;
#pragma unroll
      for (int u = 0; u < HU; ++u) s += g_lds[u][tid];
      g_part[ot][gj][bg0 + tid] = s;
    }
    gbar(++nbar, false, 0);
  }
}

__global__ void __launch_bounds__(256) k_reduce(const float* __restrict__ b_fc,
                                                float* __restrict__ out) {
  int id = blockIdx.x * 256 + threadIdx.x;
  if (id >= B * OUTL) return;
  int b = id / OUTL, ot = id - b * OUTL;
  float s = b_fc[0];
#pragma unroll 8
  for (int g = 0; g < GJ; ++g) s += g_part[ot][g][b];
  out[id] = s;   // out[b][ot], row-major == id
}

extern "C" void kernel_launch(void* const* d_in, const int* in_sizes, int n_in,
                              void* d_out, int out_size, void* d_ws, size_t ws_size,
                              hipStream_t stream) {
  (void)in_sizes; (void)n_in; (void)d_ws; (void)ws_size; (void)out_size;
  const float* input = (const float*)d_in[0];
  const float* covar = (const float*)d_in[1];
  const float* W_ih1 = (const float*)d_in[2];
  const float* W_hh1 = (const float*)d_in[3];
  const float* b1    = (const float*)d_in[4];
  const float* W_ih2 = (const float*)d_in[5];
  const float* W_hh2 = (const float*)d_in[6];
  const float* b2    = (const float*)d_in[7];
  const float* W_fc  = (const float*)d_in[8];
  const float* b_fc  = (const float*)d_in[9];

  k_init<<<dim3(1), dim3(256), 0, stream>>>();
  k_lstm<<<dim3(NWG), dim3(NT), 0, stream>>>(input, covar, W_ih1, W_hh1, b1,
                                             W_ih2, W_hh2, b2, W_fc);
  k_reduce<<<dim3((B * OUTL + 255) / 256), dim3(256), 0, stream>>>(
      b_fc, (float*)d_out);
}

// Round 5
// 3560.782 us; speedup vs baseline: 4.0936x; 1.3682x over previous
//
#include <hip/hip_runtime.h>

// ---------------------------------------------------------------------------
// multiStepModel: LSTM encoder (T=365) -> relu -> constant-input LSTM decoder
// (90 steps) -> relu -> FC.  Persistent cooperative kernel, 1 WG/CU.
// R5: gate GEMM via v_mfma_f32_16x16x32_f16 with split-precision operands
// (x = x_hi + x_lo in f16; 3 MFMA terms, fp32 accumulate ~ fp32 accuracy).
// W hi/lo LDS-resident; h exchanged through LLC as packed (hi16|lo16) u32
// via relaxed AGENT-scope atomics (R4-proven coherence path, half the bytes).
// XOR-swizzled LDS slots -> conflict-optimal ds_read_b128.
// ---------------------------------------------------------------------------

namespace {
constexpr int B = 128, T = 365, IN = 64, COV = 256, H = 512, OUTL = 90;
constexpr int GB = 4;            // batch groups (independent barrier quorums)
constexpr int GJ = 64;           // hidden groups
constexpr int NWG = GB * GJ;     // 256 workgroups, 1/CU
constexpr int NT = 256;          // threads per WG (4 waves)
constexpr int BS = B / GB;       // 32 batch rows per WG
constexpr int HU = H / GJ;       // 8 hidden units per WG
constexpr int NR = 4 * HU;       // 32 gate rows per WG
constexpr int KS = 576;          // hh K (512) + x K (64)
constexpr int NSLOT_H = 64;      // 512 / 8 : 16B slots of the h part
constexpr int NSLOT = 72;        // 576 / 8 : total 16B slots per row
}

using ull = unsigned long long;
typedef __attribute__((ext_vector_type(8))) short short8;
typedef __attribute__((ext_vector_type(8))) _Float16 half8;
typedef __attribute__((ext_vector_type(4))) float f32x4;

__device__ unsigned int g_h[2][B][H];      // packed f16 (hi<<16|lo) hidden state
__device__ float g_part[OUTL][GJ][B];      // per-hidden-group FC partials
__device__ int   g_flag[GB][64];           // per-WG monotonic barrier flags

__device__ __forceinline__ float sigf(float x) { return 1.0f / (1.0f + expf(-x)); }

__device__ __forceinline__ float4 fma4(float4 a, float4 b, float4 c) {
  c.x = fmaf(a.x, b.x, c.x); c.y = fmaf(a.y, b.y, c.y);
  c.z = fmaf(a.z, b.z, c.z); c.w = fmaf(a.w, b.w, c.w);
  return c;
}
__device__ __forceinline__ float hsum4(float4 a) { return (a.x + a.y) + (a.z + a.w); }

// fp32 -> (f16 hi, f16 lo) split, packed hi in top 16 bits.
__device__ __forceinline__ unsigned int pack_split(float v) {
  _Float16 hi = (_Float16)v;
  _Float16 lo = (_Float16)(v - (float)hi);
  return ((unsigned int)__builtin_bit_cast(unsigned short, hi) << 16) |
         (unsigned int)__builtin_bit_cast(unsigned short, lo);
}
__device__ __forceinline__ float unpack_split(unsigned int u) {
  _Float16 hi = __builtin_bit_cast(_Float16, (unsigned short)(u >> 16));
  _Float16 lo = __builtin_bit_cast(_Float16, (unsigned short)(u & 0xFFFFu));
  return (float)hi + (float)lo;
}

__global__ void __launch_bounds__(256) k_init() {
  int t = threadIdx.x;
  if (t < GB * 64) g_flag[t >> 6][t & 63] = 0;
}

__global__ void __launch_bounds__(NT, 1) k_lstm(
    const float* __restrict__ input, const float* __restrict__ covar,
    const float* __restrict__ W_ih1, const float* __restrict__ W_hh1,
    const float* __restrict__ b1,    const float* __restrict__ W_ih2,
    const float* __restrict__ W_hh2, const float* __restrict__ b2,
    const float* __restrict__ W_fc) {
  // f16 hi/lo operand tiles.  Slot s (16B = 8 halves) of row r lives at
  // column (s ^ (r&7)) -> conflict-optimal b128 reads (T2-style XOR swizzle).
  __shared__ __align__(16) short wH[NR][NSLOT * 8];   // W hi   (36.9 KB)
  __shared__ __align__(16) short wL[NR][NSLOT * 8];   // W lo
  __shared__ __align__(16) short bH[BS][NSLOT * 8];   // [h;x] hi
  __shared__ __align__(16) short bL[BS][NSLOT * 8];   // [h;x] lo
  __shared__ float g_lds[NR][33];                     // gate preacts fp32
  __shared__ float pb_lds[NR][33];                    // covproj+b1 / proj2

  const int tid = threadIdx.x;
  const int gb  = blockIdx.x & (GB - 1);
  const int gj  = blockIdx.x >> 2;
  const int bg0 = gb * BS;
  const int j0  = gj * HU;

  const int ub = tid & 31;       // cell mapping: one (batch,unit) per thread
  const int uu = tid >> 5;
  const int bl = tid >> 3;       // staging: row 0..31
  const int sg = tid & 7;        // staging: slot phase 0..7
  const int bt = tid & 15;       // fp32 (cov/proj2) mapping
  const int rt = tid >> 4;

  // MFMA mapping: wave w owns D tile rows [rows0,rows0+16) x cols [cols0,+16)
  const int lane  = tid & 63;
  const int wv    = tid >> 6;
  const int rows0 = (wv >> 1) * 16;
  const int cols0 = (wv & 1) * 16;
  const int ra    = rows0 + (lane & 15);   // A row (gate)
  const int rb    = cols0 + (lane & 15);   // B col (batch)
  const int cc    = lane >> 4;             // k-chunk 0..3
  const int x7    = lane & 7;              // swizzle key (== ra&7 == rb&7)

  int nbar = 0;

  // ---- one slot (8 fp32 -> f16 hi/lo) into a pair of LDS tiles ----
  auto put_slot = [&](short (*dH)[NSLOT * 8], short (*dL)[NSLOT * 8],
                      int r, int s, const float* src) {
    float4 p0 = ((const float4*)src)[0], p1 = ((const float4*)src)[1];
    float f[8] = {p0.x, p0.y, p0.z, p0.w, p1.x, p1.y, p1.z, p1.w};
    short8 hi, lo;
#pragma unroll
    for (int j = 0; j < 8; ++j) {
      _Float16 h_ = (_Float16)f[j];
      _Float16 l_ = (_Float16)(f[j] - (float)h_);
      hi[j] = __builtin_bit_cast(short, h_);
      lo[j] = __builtin_bit_cast(short, l_);
    }
    const int s2 = s ^ (r & 7);
    *(short8*)&dH[r][s2 * 8] = hi;
    *(short8*)&dL[r][s2 * 8] = lo;
  };

  // ---- per-gb-group barrier (R4-proven).  Release = __syncthreads (drains
  // vmcnt) + per-WG flag atomicExch.  No fences: h reads are AGENT-scope.
  auto gbar = [&](int nb, bool with_x, int tn) {
    __syncthreads();
    if (tid == 0) atomicExch(&g_flag[gb][gj], nb);
    if (with_x) {   // stage x_{tn} into B slots 64..71 during the wait
      const float* src = input + ((size_t)(bg0 + bl) * T + tn) * IN + sg * 8;
      put_slot(bH, bL, bl, NSLOT_H + sg, src);
    }
    if (tid < 64) {
      while (__hip_atomic_load(&g_flag[gb][tid], __ATOMIC_RELAXED,
                               __HIP_MEMORY_SCOPE_AGENT) < nb)
        __builtin_amdgcn_s_sleep(1);
    }
    __syncthreads();
  };

  // ---- stage W (hi/lo) into LDS ----
  auto stage_w_hh = [&](const float* Whh) {
    for (int idx = tid; idx < NR * NSLOT_H; idx += NT) {
      const int r = idx >> 6, s = idx & 63;
      const int grow = (r >> 3) * H + j0 + (r & 7);
      put_slot(wH, wL, r, s, Whh + (size_t)grow * H + s * 8);
    }
  };
  stage_w_hh(W_hh1);
  for (int idx = tid; idx < NR * 8; idx += NT) {   // x cols of W_ih1
    const int r = idx >> 3, s = NSLOT_H + (idx & 7);
    const int grow = (r >> 3) * H + j0 + (r & 7);
    put_slot(wH, wL, r, s, W_ih1 + (size_t)grow * (IN + COV) + (s - NSLOT_H) * 8);
  }

  // ---- covariate projection + b1 (constant over t) -> pb_lds (fp32) ----
  {
    const int r0 = rt, r1 = rt + 16;
    const int row0 = (r0 >> 3) * H + j0 + (r0 & 7);
    const int row1 = (r1 >> 3) * H + j0 + (r1 & 7);
    const float4* c0 = (const float4*)(covar + (size_t)(bg0 + bt) * COV);
    const float4* c1 = (const float4*)(covar + (size_t)(bg0 + bt + 16) * COV);
    const float4* w0 = (const float4*)(W_ih1 + (size_t)row0 * (IN + COV) + IN);
    const float4* w1 = (const float4*)(W_ih1 + (size_t)row1 * (IN + COV) + IN);
    float4 a00 = {0, 0, 0, 0}, a01 = a00, a10 = a00, a11 = a00;
    for (int k = 0; k < COV / 4; ++k) {
      float4 va = c0[k], vb = c1[k], wa = w0[k], wb = w1[k];
      a00 = fma4(va, wa, a00); a01 = fma4(va, wb, a01);
      a10 = fma4(vb, wa, a10); a11 = fma4(vb, wb, a11);
    }
    pb_lds[r0][bt]      = hsum4(a00) + b1[row0];
    pb_lds[r1][bt]      = hsum4(a01) + b1[row1];
    pb_lds[r0][bt + 16] = hsum4(a10) + b1[row0];
    pb_lds[r1][bt + 16] = hsum4(a11) + b1[row1];
  }

  float c_state = 0.0f;
  const float wfc = W_fc[j0 + uu];

  // ---- packed-h load (LLC, agent scope) + commit (unpack -> swizzled LDS) --
  auto load_h = [&](int par, ull (&tmp)[32]) {
    const ull* hr = (const ull*)&g_h[par][bg0 + bl][0];
#pragma unroll
    for (int i = 0; i < 8; ++i)
#pragma unroll
      for (int q = 0; q < 4; ++q)
        tmp[i * 4 + q] = __hip_atomic_load(hr + (sg + 8 * i) * 4 + q,
                                           __ATOMIC_RELAXED,
                                           __HIP_MEMORY_SCOPE_AGENT);
  };
  auto commit_h = [&](ull (&tmp)[32]) {
#pragma unroll
    for (int i = 0; i < 8; ++i) {
      short8 hi, lo;
#pragma unroll
      for (int q = 0; q < 4; ++q) {
        const ull v = tmp[i * 4 + q];
        const unsigned int u0 = (unsigned int)v, u1 = (unsigned int)(v >> 32);
        hi[2 * q]     = (short)(u0 >> 16);  lo[2 * q]     = (short)(u0 & 0xFFFFu);
        hi[2 * q + 1] = (short)(u1 >> 16);  lo[2 * q + 1] = (short)(u1 & 0xFFFFu);
      }
      const int s = sg + 8 * i, s2 = s ^ (bl & 7);
      *(short8*)&bH[bl][s2 * 8] = hi;
      *(short8*)&bL[bl][s2 * 8] = lo;
    }
  };

  // ---- MFMA gate GEMM over kblocks [kb0,kb1); D -> g_lds fp32 ----
  auto mfma_step = [&](int kb0, int kb1) {
    f32x4 aA = {0.f, 0.f, 0.f, 0.f}, aB = aA, aC = aA;
    for (int kb = kb0; kb < kb1; ++kb) {
      const int s2 = (kb * 4 + cc) ^ x7;
      const half8 ah = __builtin_bit_cast(half8, *(const short8*)&wH[ra][s2 * 8]);
      const half8 al = __builtin_bit_cast(half8, *(const short8*)&wL[ra][s2 * 8]);
      const half8 bh = __builtin_bit_cast(half8, *(const short8*)&bH[rb][s2 * 8]);
      const half8 bo = __builtin_bit_cast(half8, *(const short8*)&bL[rb][s2 * 8]);
      aA = __builtin_amdgcn_mfma_f32_16x16x32_f16(ah, bh, aA, 0, 0, 0);
      aB = __builtin_amdgcn_mfma_f32_16x16x32_f16(ah, bo, aB, 0, 0, 0);
      aC = __builtin_amdgcn_mfma_f32_16x16x32_f16(al, bh, aC, 0, 0, 0);
    }
    const int drow = rows0 + (lane >> 4) * 4;   // m89: row=(lane>>4)*4+reg
    const int dcol = cols0 + (lane & 15);       //      col=lane&15
#pragma unroll
    for (int r = 0; r < 4; ++r)
      g_lds[drow + r][dcol] = aA[r] + aB[r] + aC[r];
  };

  // ---- pointwise LSTM cell; h' split+packed, published AGENT-scope ----
  auto cell_update = [&](int wbuf, bool relu_store) -> float {
    float ip = g_lds[uu][ub]      + pb_lds[uu][ub];
    float fp = g_lds[8 + uu][ub]  + pb_lds[8 + uu][ub];
    float gp = g_lds[16 + uu][ub] + pb_lds[16 + uu][ub];
    float op = g_lds[24 + uu][ub] + pb_lds[24 + uu][ub];
    c_state = sigf(fp) * c_state + sigf(ip) * tanhf(gp);
    float hv = sigf(op) * tanhf(c_state);
    __hip_atomic_store(&g_h[wbuf][bg0 + ub][j0 + uu],
                       pack_split(relu_store ? fmaxf(hv, 0.0f) : hv),
                       __ATOMIC_RELAXED, __HIP_MEMORY_SCOPE_AGENT);
    return hv;
  };

  // =================== encoder: 365 steps ===================
  {  // stage x_0 into B slots 64..71
    const float* src = input + (size_t)(bg0 + bl) * T * IN + sg * 8;
    put_slot(bH, bL, bl, NSLOT_H + sg, src);
  }
  for (int t = 0; t < T; ++t) {
    if (t > 0) {
      ull tmp[32];
      load_h(t & 1, tmp);     // issue all 32 LLC loads, then unpack+commit
      commit_h(tmp);
    }
    __syncthreads();                          // B tile ready; g_lds free
    mfma_step(t > 0 ? 0 : 16, 18);            // t==0: x part only (h=0)
    __syncthreads();
    cell_update((t + 1) & 1, t == T - 1);     // last step stores relu(h_enc)
    gbar(++nbar, t + 1 < T, t + 1);           // stage x_{t+1} in the wait
  }

  // ====== transition: proj2 = [relu(h_enc),covar] @ W_ih2^T + b2 (fp32) ======
  {
    const int b0 = bt, b1v = bt + 16;
    const int r0 = rt, r1 = rt + 16;
    const int row0 = (r0 >> 3) * H + j0 + (r0 & 7);
    const int row1 = (r1 >> 3) * H + j0 + (r1 & 7);
    const float* w0 = W_ih2 + (size_t)row0 * (H + COV);
    const float* w1 = W_ih2 + (size_t)row1 * (H + COV);
    const ull* h0 = (const ull*)&g_h[1][bg0 + b0][0];
    const ull* h1 = (const ull*)&g_h[1][bg0 + b1v][0];
    float a00 = 0.f, a01 = 0.f, a10 = 0.f, a11 = 0.f;
    for (int m = 0; m < H / 2; ++m) {   // h part from packed LLC state
      const ull v0 = __hip_atomic_load(h0 + m, __ATOMIC_RELAXED,
                                       __HIP_MEMORY_SCOPE_AGENT);
      const ull v1 = __hip_atomic_load(h1 + m, __ATOMIC_RELAXED,
                                       __HIP_MEMORY_SCOPE_AGENT);
      const float h00 = unpack_split((unsigned int)v0);
      const float h01 = unpack_split((unsigned int)(v0 >> 32));
      const float h10 = unpack_split((unsigned int)v1);
      const float h11 = unpack_split((unsigned int)(v1 >> 32));
      const float wa0 = w0[2 * m], wa1 = w0[2 * m + 1];
      const float wb0 = w1[2 * m], wb1 = w1[2 * m + 1];
      a00 += h00 * wa0 + h01 * wa1;  a01 += h00 * wb0 + h01 * wb1;
      a10 += h10 * wa0 + h11 * wa1;  a11 += h10 * wb0 + h11 * wb1;
    }
    {  // covar part (fp32, cache-hot)
      const float4* c0 = (const float4*)(covar + (size_t)(bg0 + b0) * COV);
      const float4* c1 = (const float4*)(covar + (size_t)(bg0 + b1v) * COV);
      const float4* W0 = (const float4*)w0;
      const float4* W1 = (const float4*)w1;
      float4 s00 = {0, 0, 0, 0}, s01 = s00, s10 = s00, s11 = s00;
      for (int k = 0; k < COV / 4; ++k) {
        float4 ha = c0[k], hb = c1[k], wa = W0[H / 4 + k], wb = W1[H / 4 + k];
        s00 = fma4(ha, wa, s00); s01 = fma4(ha, wb, s01);
        s10 = fma4(hb, wa, s10); s11 = fma4(hb, wb, s11);
      }
      a00 += hsum4(s00); a01 += hsum4(s01);
      a10 += hsum4(s10); a11 += hsum4(s11);
    }
    pb_lds[r0][b0]  = a00 + b2[row0];
    pb_lds[r1][b0]  = a01 + b2[row1];
    pb_lds[r0][b1v] = a10 + b2[row0];
    pb_lds[r1][b1v] = a11 + b2[row1];
  }
  stage_w_hh(W_hh2);   // decoder recurrent weights over encoder ones
  c_state = 0.0f;
  gbar(++nbar, false, 0);   // protects g_h[1] (read above) from ot=0 write

  // =================== decoder: 90 steps ===================
  for (int ot = 0; ot < OUTL; ++ot) {
    if (ot > 0) {
      ull tmp[32];
      load_h(ot & 1, tmp);
      commit_h(tmp);
    }
    __syncthreads();
    mfma_step(0, ot > 0 ? 16 : 0);   // ot==0: gates = proj2 only (D=0)
    __syncthreads();
    float hv = cell_update((ot + 1) & 1, false);
    float fcv = fmaxf(hv, 0.0f) * wfc;   // relu(h) * W_fc[j]
    __syncthreads();                     // g_lds reuse guard
    g_lds[uu][ub] = fcv;                 // rows 0..7 hold FC partials
    __syncthreads();
    if (tid < BS) {
      float s = 0.0f;
#pragma unroll
      for (int u = 0; u < HU; ++u) s += g_lds[u][tid];
      g_part[ot][gj][bg0 + tid] = s;
    }
    gbar(++nbar, false, 0);
  }
}

__global__ void __launch_bounds__(256) k_reduce(const float* __restrict__ b_fc,
                                                float* __restrict__ out) {
  int id = blockIdx.x * 256 + threadIdx.x;
  if (id >= B * OUTL) return;
  int b = id / OUTL, ot = id - b * OUTL;
  float s = b_fc[0];
#pragma unroll 8
  for (int g = 0; g < GJ; ++g) s += g_part[ot][g][b];
  out[id] = s;   // out[b][ot], row-major == id
}

extern "C" void kernel_launch(void* const* d_in, const int* in_sizes, int n_in,
                              void* d_out, int out_size, void* d_ws, size_t ws_size,
                              hipStream_t stream) {
  (void)in_sizes; (void)n_in; (void)d_ws; (void)ws_size; (void)out_size;
  const float* input = (const float*)d_in[0];
  const float* covar = (const float*)d_in[1];
  const float* W_ih1 = (const float*)d_in[2];
  const float* W_hh1 = (const float*)d_in[3];
  const float* b1    = (const float*)d_in[4];
  const float* W_ih2 = (const float*)d_in[5];
  const float* W_hh2 = (const float*)d_in[6];
  const float* b2    = (const float*)d_in[7];
  const float* W_fc  = (const float*)d_in[8];
  const float* b_fc  = (const float*)d_in[9];

  k_init<<<dim3(1), dim3(256), 0, stream>>>();
  k_lstm<<<dim3(NWG), dim3(NT), 0, stream>>>(input, covar, W_ih1, W_hh1, b1,
                                             W_ih2, W_hh2, b2, W_fc);
  k_reduce<<<dim3((B * OUTL + 255) / 256), dim3(256), 0, stream>>>(
      b_fc, (float*)d_out);
}